// Round 1
// baseline (122.228 us; speedup 1.0000x reference)
//
#include <hip/hip_runtime.h>
#include <hip/hip_bf16.h>

#define N 8192
#define FIN 256
#define FOUT 64
#define NSLICE 8
#define SLICE_J (N / NSLICE) /* 1024 */
#define NEG_INF -9.0e15f

typedef __attribute__((ext_vector_type(8))) short short8;
typedef __attribute__((ext_vector_type(4))) float f32x4;

static __device__ __forceinline__ short f2bf(float v) {
    __hip_bfloat16 b = __float2bfloat16(v);
    return __builtin_bit_cast(short, b);
}
static __device__ __forceinline__ float bf2f(short s) {
    unsigned u = ((unsigned)(unsigned short)s) << 16;
    return __builtin_bit_cast(float, u);
}

// ---------------- k1: Wh = h @ W, s1 = Wh@a1, s2 = Wh@a2 ----------------
__global__ __launch_bounds__(256) void k_wh(const float* __restrict__ h,
                                            const float* __restrict__ W,
                                            const float* __restrict__ a,
                                            float* __restrict__ Wh,
                                            float* __restrict__ s1,
                                            float* __restrict__ s2) {
    int wave = threadIdx.x >> 6, lane = threadIdx.x & 63;
    int i = blockIdx.x * 4 + wave;
    const float* hrow = h + (size_t)i * FIN;
    float acc = 0.f;
#pragma unroll 8
    for (int k = 0; k < FIN; k += 4) {
        float4 hv = *(const float4*)(hrow + k);
        acc += hv.x * W[(k + 0) * FOUT + lane];
        acc += hv.y * W[(k + 1) * FOUT + lane];
        acc += hv.z * W[(k + 2) * FOUT + lane];
        acc += hv.w * W[(k + 3) * FOUT + lane];
    }
    Wh[(size_t)i * FOUT + lane] = acc;
    float v1 = acc * a[lane];
    float v2 = acc * a[FOUT + lane];
#pragma unroll
    for (int off = 32; off; off >>= 1) {
        v1 += __shfl_xor(v1, off);
        v2 += __shfl_xor(v2, off);
    }
    if (lane == 0) { s1[i] = v1; s2[i] = v2; }
}

// ---------------- k2: repack Wh (fp32 row-major) -> WhB (bf16 B-fragment layout) ----
// WhB[jt][ft][lane][q] = bf16( Wh[jt*32 + (lane>>4)*8 + q][ft*16 + (lane&15)] )
__global__ __launch_bounds__(256) void k_repack(const float* __restrict__ Wh,
                                                short* __restrict__ WhB) {
    int t = blockIdx.x * 256 + threadIdx.x; // 65536 total
    int lane = t & 63, ft = (t >> 6) & 3, jt = t >> 8;
    int g = lane >> 4, r = lane & 15;
    short8 w;
#pragma unroll
    for (int q = 0; q < 8; ++q) {
        float v = Wh[(size_t)(jt * 32 + g * 8 + q) * FOUT + ft * 16 + r];
        w[q] = f2bf(v);
    }
    *((short8*)WhB + t) = w;
}

// ---------------- k3: flash partial over a j-slice ----------------
// grid = (N/32 row-blocks) * NSLICE, block = 128 (2 waves, 16 rows each)
__global__ __launch_bounds__(128) void k_flash(const int* __restrict__ adj,
                                               const short* __restrict__ WhB,
                                               const float* __restrict__ s1,
                                               const float* __restrict__ s2,
                                               float* __restrict__ pO,
                                               float* __restrict__ pm,
                                               float* __restrict__ pl) {
    int rb = blockIdx.x / NSLICE, sl = blockIdx.x % NSLICE;
    int wave = threadIdx.x >> 6, lane = threadIdx.x & 63;
    int r = lane & 15, g = lane >> 4;
    int row = rb * 32 + wave * 16 + r; // row this lane computes e/p for (A-frag layout)

    __shared__ __align__(16) float s2s[SLICE_J];
    for (int t = threadIdx.x; t < SLICE_J; t += 128) s2s[t] = s2[sl * SLICE_J + t];
    __syncthreads();

    float s1i = s1[row];
    float m = NEG_INF, l = 0.f;
    f32x4 acc0 = {0.f, 0.f, 0.f, 0.f};
    f32x4 acc1 = {0.f, 0.f, 0.f, 0.f};
    f32x4 acc2 = {0.f, 0.f, 0.f, 0.f};
    f32x4 acc3 = {0.f, 0.f, 0.f, 0.f};

    const int* arow = adj + (size_t)row * N + sl * SLICE_J + g * 8;

    for (int step = 0; step < SLICE_J / 32; ++step) {
        int4 av0 = *(const int4*)(arow + step * 32);
        int4 av1 = *(const int4*)(arow + step * 32 + 4);
        float4 sv0 = *(const float4*)&s2s[step * 32 + g * 8];
        float4 sv1 = *(const float4*)&s2s[step * 32 + g * 8 + 4];

        auto ec = [&](int aval, float s2v) -> float {
            float x = s1i + s2v;
            x = x > 0.f ? x : 0.2f * x;
            return aval > 0 ? x : NEG_INF;
        };
        float e0 = ec(av0.x, sv0.x), e1 = ec(av0.y, sv0.y);
        float e2 = ec(av0.z, sv0.z), e3 = ec(av0.w, sv0.w);
        float e4 = ec(av1.x, sv1.x), e5 = ec(av1.y, sv1.y);
        float e6 = ec(av1.z, sv1.z), e7 = ec(av1.w, sv1.w);

        float cmax = fmaxf(fmaxf(fmaxf(e0, e1), fmaxf(e2, e3)),
                           fmaxf(fmaxf(e4, e5), fmaxf(e6, e7)));
        cmax = fmaxf(cmax, __shfl_xor(cmax, 16));
        cmax = fmaxf(cmax, __shfl_xor(cmax, 32));
        float mnew = fmaxf(m, cmax);
        float scale = __expf(m - mnew);

        short8 af;
        float csum = 0.f;
        {
            float p0 = __expf(e0 - mnew), p1 = __expf(e1 - mnew);
            float p2 = __expf(e2 - mnew), p3 = __expf(e3 - mnew);
            float p4 = __expf(e4 - mnew), p5 = __expf(e5 - mnew);
            float p6 = __expf(e6 - mnew), p7 = __expf(e7 - mnew);
            af[0] = f2bf(p0); af[1] = f2bf(p1); af[2] = f2bf(p2); af[3] = f2bf(p3);
            af[4] = f2bf(p4); af[5] = f2bf(p5); af[6] = f2bf(p6); af[7] = f2bf(p7);
            csum = bf2f(af[0]) + bf2f(af[1]) + bf2f(af[2]) + bf2f(af[3]) +
                   bf2f(af[4]) + bf2f(af[5]) + bf2f(af[6]) + bf2f(af[7]);
        }
        csum += __shfl_xor(csum, 16);
        csum += __shfl_xor(csum, 32);
        l = l * scale + csum;
        m = mnew;

        // rescale O: lane holds C rows g*4+0..3; scale for row q lives in lane q (q<16)
        float sc0 = __shfl(scale, g * 4 + 0);
        float sc1 = __shfl(scale, g * 4 + 1);
        float sc2 = __shfl(scale, g * 4 + 2);
        float sc3 = __shfl(scale, g * 4 + 3);
        acc0[0] *= sc0; acc0[1] *= sc1; acc0[2] *= sc2; acc0[3] *= sc3;
        acc1[0] *= sc0; acc1[1] *= sc1; acc1[2] *= sc2; acc1[3] *= sc3;
        acc2[0] *= sc0; acc2[1] *= sc1; acc2[2] *= sc2; acc2[3] *= sc3;
        acc3[0] *= sc0; acc3[1] *= sc1; acc3[2] *= sc2; acc3[3] *= sc3;

        int jt = sl * (SLICE_J / 32) + step;
        const short8* bp = (const short8*)WhB + (size_t)jt * 256 + lane;
        acc0 = __builtin_amdgcn_mfma_f32_16x16x32_bf16(af, bp[0], acc0, 0, 0, 0);
        acc1 = __builtin_amdgcn_mfma_f32_16x16x32_bf16(af, bp[64], acc1, 0, 0, 0);
        acc2 = __builtin_amdgcn_mfma_f32_16x16x32_bf16(af, bp[128], acc2, 0, 0, 0);
        acc3 = __builtin_amdgcn_mfma_f32_16x16x32_bf16(af, bp[192], acc3, 0, 0, 0);
    }

    // write partials: C layout col=lane&15, rows (lane>>4)*4+reg
    int base_row = rb * 32 + wave * 16;
    f32x4 accs[4] = {acc0, acc1, acc2, acc3};
#pragma unroll
    for (int nt = 0; nt < 4; ++nt) {
#pragma unroll
        for (int reg = 0; reg < 4; ++reg) {
            int orow = base_row + g * 4 + reg;
            pO[((size_t)orow * NSLICE + sl) * FOUT + nt * 16 + r] = accs[nt][reg];
        }
    }
    if (lane < 16) {
        pm[(size_t)row * NSLICE + sl] = m;
        pl[(size_t)row * NSLICE + sl] = l;
    }
}

// ---------------- k4: merge partials + ELU ----------------
__global__ __launch_bounds__(256) void k_merge(const float* __restrict__ pO,
                                               const float* __restrict__ pm,
                                               const float* __restrict__ pl,
                                               float* __restrict__ out) {
    int t = blockIdx.x * 256 + threadIdx.x;
    int row = t >> 6, f = t & 63;
    float ms[NSLICE];
    float M = NEG_INF;
#pragma unroll
    for (int s = 0; s < NSLICE; ++s) {
        ms[s] = pm[(size_t)row * NSLICE + s];
        M = fmaxf(M, ms[s]);
    }
    float L = 0.f, O = 0.f;
#pragma unroll
    for (int s = 0; s < NSLICE; ++s) {
        float w = __expf(ms[s] - M);
        L += pl[(size_t)row * NSLICE + s] * w;
        O += pO[((size_t)row * NSLICE + s) * FOUT + f] * w;
    }
    float x = O / L;
    out[t] = x > 0.f ? x : expm1f(x);
}

extern "C" void kernel_launch(void* const* d_in, const int* in_sizes, int n_in,
                              void* d_out, int out_size, void* d_ws, size_t ws_size,
                              hipStream_t stream) {
    const float* h   = (const float*)d_in[0];
    const int*   adj = (const int*)d_in[1];
    const float* W   = (const float*)d_in[2];
    const float* a   = (const float*)d_in[3];
    float* out = (float*)d_out;

    char* ws = (char*)d_ws;
    float* Wh  = (float*)ws;                          // 2 MB
    short* WhB = (short*)(ws + (2u << 20));           // 1 MB
    float* s1  = (float*)(ws + (3u << 20));           // 32 KB
    float* s2  = (float*)(ws + (3u << 20) + 32768);   // 32 KB
    float* pO  = (float*)(ws + (4u << 20));           // 16 MB
    float* pm  = (float*)(ws + (20u << 20));          // 256 KB
    float* pl  = (float*)(ws + (20u << 20) + (256u << 10)); // 256 KB

    k_wh<<<N / 4, 256, 0, stream>>>(h, W, a, Wh, s1, s2);
    k_repack<<<(N / 32) * 4 * 64 / 256, 256, 0, stream>>>(Wh, WhB);
    k_flash<<<(N / 32) * NSLICE, 128, 0, stream>>>(adj, WhB, s1, s2, pO, pm, pl);
    k_merge<<<N * FOUT / 256, 256, 0, stream>>>(pO, pm, pl, out);
}

// Round 3
// 121.965 us; speedup vs baseline: 1.0022x; 1.0022x over previous
//
#include <hip/hip_runtime.h>
#include <hip/hip_bf16.h>

#define N 8192
#define FIN 256
#define FOUT 64
#define NSLICE 8
#define SLICE_J (N / NSLICE) /* 1024 */
#define NEG_INF -9.0e15f
#define L2E 1.4426950408889634f

typedef __attribute__((ext_vector_type(8))) short short8;
typedef __attribute__((ext_vector_type(4))) float f32x4;

static __device__ __forceinline__ short f2bf(float v) {
    __hip_bfloat16 b = __float2bfloat16(v);
    return __builtin_bit_cast(short, b);
}
static __device__ __forceinline__ float bf2f(short s) {
    unsigned u = ((unsigned)(unsigned short)s) << 16;
    return __builtin_bit_cast(float, u);
}
static __device__ __forceinline__ float exp2fast(float x) {
    return __builtin_amdgcn_exp2f(x); // v_exp_f32: 2^x
}

// ---------------- k1: Wh = h @ W; s1' = (Wh@a1)*log2e; s2' = (Wh@a2)*log2e ----
__global__ __launch_bounds__(256) void k_wh(const float* __restrict__ h,
                                            const float* __restrict__ W,
                                            const float* __restrict__ a,
                                            float* __restrict__ Wh,
                                            float* __restrict__ s1,
                                            float* __restrict__ s2) {
    int wave = threadIdx.x >> 6, lane = threadIdx.x & 63;
    int i = blockIdx.x * 4 + wave;
    const float* hrow = h + (size_t)i * FIN;
    float acc = 0.f;
#pragma unroll 8
    for (int k = 0; k < FIN; k += 4) {
        float4 hv = *(const float4*)(hrow + k);
        acc += hv.x * W[(k + 0) * FOUT + lane];
        acc += hv.y * W[(k + 1) * FOUT + lane];
        acc += hv.z * W[(k + 2) * FOUT + lane];
        acc += hv.w * W[(k + 3) * FOUT + lane];
    }
    Wh[(size_t)i * FOUT + lane] = acc;
    float v1 = acc * a[lane];
    float v2 = acc * a[FOUT + lane];
#pragma unroll
    for (int off = 32; off; off >>= 1) {
        v1 += __shfl_xor(v1, off);
        v2 += __shfl_xor(v2, off);
    }
    if (lane == 0) { s1[i] = v1 * L2E; s2[i] = v2 * L2E; }
}

// ---------------- k1b: maxs2 = max_j s2'[j] (single block) ----------------
__global__ __launch_bounds__(256) void k_max(const float* __restrict__ s2,
                                             float* __restrict__ maxs2) {
    int t = threadIdx.x;
    float m = NEG_INF;
    for (int i = t; i < N; i += 256) m = fmaxf(m, s2[i]);
#pragma unroll
    for (int off = 32; off; off >>= 1) m = fmaxf(m, __shfl_xor(m, off));
    __shared__ float red[4];
    if ((t & 63) == 0) red[t >> 6] = m;
    __syncthreads();
    if (t == 0) {
        float r = fmaxf(fmaxf(red[0], red[1]), fmaxf(red[2], red[3]));
        maxs2[0] = r;
    }
}

// ---------------- k2: repack Wh (fp32 row-major) -> WhB (bf16 B-fragment layout) ----
// WhB[jt][ft][lane][q] = bf16( Wh[jt*32 + (lane>>4)*8 + q][ft*16 + (lane&15)] )
__global__ __launch_bounds__(256) void k_repack(const float* __restrict__ Wh,
                                                short* __restrict__ WhB) {
    int t = blockIdx.x * 256 + threadIdx.x; // 65536 total
    int lane = t & 63, ft = (t >> 6) & 3, jt = t >> 8;
    int g = lane >> 4, r = lane & 15;
    short8 w;
#pragma unroll
    for (int q = 0; q < 8; ++q) {
        float v = Wh[(size_t)(jt * 32 + g * 8 + q) * FOUT + ft * 16 + r];
        w[q] = f2bf(v);
    }
    *((short8*)WhB + t) = w;
}

// ---------------- k3: partial-softmax attention over a j-slice ----------------
// Fixed per-row max M'_i = lrelu(s1'_i + max_j s2'_j)  (valid upper bound, tight
// for a dense random graph) -> no online rescale, no cross-lane ops in the loop.
// grid = (N/32 row-blocks) * NSLICE, block = 128 (2 waves, 16 rows each)
__global__ __launch_bounds__(128) void k_flash(const int* __restrict__ adj,
                                               const short* __restrict__ WhB,
                                               const float* __restrict__ s1,
                                               const float* __restrict__ s2,
                                               const float* __restrict__ maxs2,
                                               float* __restrict__ pO,
                                               float* __restrict__ pl) {
    int rb = blockIdx.x / NSLICE, sl = blockIdx.x % NSLICE;
    int wave = threadIdx.x >> 6, lane = threadIdx.x & 63;
    int r = lane & 15, g = lane >> 4;
    int row = rb * 32 + wave * 16 + r; // row this lane computes p for (A-frag layout)

    __shared__ __align__(16) float s2s[SLICE_J];
    for (int t = threadIdx.x; t < SLICE_J; t += 128) s2s[t] = s2[sl * SLICE_J + t];
    __syncthreads();

    float s1i = s1[row];
    float xm = s1i + maxs2[0];
    float Mp = fmaxf(xm, 0.2f * xm); // lrelu in log2 domain (scale>0 commutes)

    float l = 0.f;
    f32x4 acc0 = {0.f, 0.f, 0.f, 0.f};
    f32x4 acc1 = {0.f, 0.f, 0.f, 0.f};
    f32x4 acc2 = {0.f, 0.f, 0.f, 0.f};
    f32x4 acc3 = {0.f, 0.f, 0.f, 0.f};

    const int* arow = adj + (size_t)row * N + sl * SLICE_J + g * 8;

#pragma unroll 2
    for (int step = 0; step < SLICE_J / 32; ++step) {
        int4 av0 = *(const int4*)(arow + step * 32);
        int4 av1 = *(const int4*)(arow + step * 32 + 4);
        float4 sv0 = *(const float4*)&s2s[step * 32 + g * 8];
        float4 sv1 = *(const float4*)&s2s[step * 32 + g * 8 + 4];

        short8 af;
        auto pc = [&](int aval, float s2v) -> short {
            float x = s1i + s2v;
            float lr = fmaxf(x, 0.2f * x);      // leaky_relu (log2-scaled domain)
            float p = exp2fast(lr - Mp);        // exp(e - M)
            p = aval > 0 ? p : 0.f;
            return f2bf(p);
        };
        af[0] = pc(av0.x, sv0.x); af[1] = pc(av0.y, sv0.y);
        af[2] = pc(av0.z, sv0.z); af[3] = pc(av0.w, sv0.w);
        af[4] = pc(av1.x, sv1.x); af[5] = pc(av1.y, sv1.y);
        af[6] = pc(av1.z, sv1.z); af[7] = pc(av1.w, sv1.w);

        l += bf2f(af[0]) + bf2f(af[1]) + bf2f(af[2]) + bf2f(af[3]) +
             bf2f(af[4]) + bf2f(af[5]) + bf2f(af[6]) + bf2f(af[7]);

        int jt = sl * (SLICE_J / 32) + step;
        const short8* bp = (const short8*)WhB + (size_t)jt * 256 + lane;
        acc0 = __builtin_amdgcn_mfma_f32_16x16x32_bf16(af, bp[0], acc0, 0, 0, 0);
        acc1 = __builtin_amdgcn_mfma_f32_16x16x32_bf16(af, bp[64], acc1, 0, 0, 0);
        acc2 = __builtin_amdgcn_mfma_f32_16x16x32_bf16(af, bp[128], acc2, 0, 0, 0);
        acc3 = __builtin_amdgcn_mfma_f32_16x16x32_bf16(af, bp[192], acc3, 0, 0, 0);
    }

    // reduce l across the 4 k-groups (same row lives in lanes r, r+16, r+32, r+48)
    l += __shfl_xor(l, 16);
    l += __shfl_xor(l, 32);

    // write partials: C layout col=lane&15, rows (lane>>4)*4+reg
    int base_row = rb * 32 + wave * 16;
    f32x4 accs[4] = {acc0, acc1, acc2, acc3};
#pragma unroll
    for (int nt = 0; nt < 4; ++nt) {
#pragma unroll
        for (int reg = 0; reg < 4; ++reg) {
            int orow = base_row + g * 4 + reg;
            pO[((size_t)orow * NSLICE + sl) * FOUT + nt * 16 + r] = accs[nt][reg];
        }
    }
    if (lane < 16) pl[(size_t)row * NSLICE + sl] = l;
}

// ---------------- k4: merge partials (plain sum now) + ELU ----------------
__global__ __launch_bounds__(256) void k_merge(const float* __restrict__ pO,
                                               const float* __restrict__ pl,
                                               float* __restrict__ out) {
    int t = blockIdx.x * 256 + threadIdx.x;
    int row = t >> 6, f = t & 63;
    float L = 0.f, O = 0.f;
#pragma unroll
    for (int s = 0; s < NSLICE; ++s) {
        L += pl[(size_t)row * NSLICE + s];
        O += pO[((size_t)row * NSLICE + s) * FOUT + f];
    }
    float x = O / L;
    out[t] = x > 0.f ? x : expm1f(x);
}

extern "C" void kernel_launch(void* const* d_in, const int* in_sizes, int n_in,
                              void* d_out, int out_size, void* d_ws, size_t ws_size,
                              hipStream_t stream) {
    const float* h   = (const float*)d_in[0];
    const int*   adj = (const int*)d_in[1];
    const float* W   = (const float*)d_in[2];
    const float* a   = (const float*)d_in[3];
    float* out = (float*)d_out;

    char* ws = (char*)d_ws;
    float* Wh    = (float*)ws;                          // 2 MB
    short* WhB   = (short*)(ws + (2u << 20));           // 1 MB
    float* s1    = (float*)(ws + (3u << 20));           // 32 KB
    float* s2    = (float*)(ws + (3u << 20) + 32768);   // 32 KB
    float* maxs2 = (float*)(ws + (3u << 20) + 65536);   // 4 B
    float* pO    = (float*)(ws + (4u << 20));           // 16 MB
    float* pl    = (float*)(ws + (20u << 20));          // 256 KB

    k_wh<<<N / 4, 256, 0, stream>>>(h, W, a, Wh, s1, s2);
    k_max<<<1, 256, 0, stream>>>(s2, maxs2);
    k_repack<<<(N / 32) * 4 * 64 / 256, 256, 0, stream>>>(Wh, WhB);
    k_flash<<<(N / 32) * NSLICE, 128, 0, stream>>>(adj, WhB, s1, s2, maxs2, pO, pl);
    k_merge<<<N * FOUT / 256, 256, 0, stream>>>(pO, pl, out);
}

// Round 4
// 120.145 us; speedup vs baseline: 1.0173x; 1.0152x over previous
//
#include <hip/hip_runtime.h>
#include <hip/hip_bf16.h>

#define N 8192
#define FIN 256
#define FOUT 64
#define NSLICE 8
#define SLICE_J (N / NSLICE) /* 1024 */
#define NEG_INF -9.0e15f
#define L2E 1.4426950408889634f

typedef __attribute__((ext_vector_type(8))) short short8;
typedef __attribute__((ext_vector_type(4))) float f32x4;

static __device__ __forceinline__ short f2bf(float v) {
    __hip_bfloat16 b = __float2bfloat16(v);
    return __builtin_bit_cast(short, b);
}
static __device__ __forceinline__ float bf2f(short s) {
    unsigned u = ((unsigned)(unsigned short)s) << 16;
    return __builtin_bit_cast(float, u);
}
static __device__ __forceinline__ float exp2fast(float x) {
    return __builtin_amdgcn_exp2f(x); // v_exp_f32: 2^x
}

// ---------------- k1: Wh = h @ W; s1' = (Wh@a1)*log2e; s2' = (Wh@a2)*log2e ----
__global__ __launch_bounds__(256) void k_wh(const float* __restrict__ h,
                                            const float* __restrict__ W,
                                            const float* __restrict__ a,
                                            float* __restrict__ Wh,
                                            float* __restrict__ s1,
                                            float* __restrict__ s2) {
    int wave = threadIdx.x >> 6, lane = threadIdx.x & 63;
    int i = blockIdx.x * 4 + wave;
    const float* hrow = h + (size_t)i * FIN;
    float acc = 0.f;
#pragma unroll 8
    for (int k = 0; k < FIN; k += 4) {
        float4 hv = *(const float4*)(hrow + k);
        acc += hv.x * W[(k + 0) * FOUT + lane];
        acc += hv.y * W[(k + 1) * FOUT + lane];
        acc += hv.z * W[(k + 2) * FOUT + lane];
        acc += hv.w * W[(k + 3) * FOUT + lane];
    }
    Wh[(size_t)i * FOUT + lane] = acc;
    float v1 = acc * a[lane];
    float v2 = acc * a[FOUT + lane];
#pragma unroll
    for (int off = 32; off; off >>= 1) {
        v1 += __shfl_xor(v1, off);
        v2 += __shfl_xor(v2, off);
    }
    if (lane == 0) { s1[i] = v1 * L2E; s2[i] = v2 * L2E; }
}

// ---------------- k1b: maxs2 = max_j s2'[j] (single block) ----------------
__global__ __launch_bounds__(256) void k_max(const float* __restrict__ s2,
                                             float* __restrict__ maxs2) {
    int t = threadIdx.x;
    float m = NEG_INF;
    for (int i = t; i < N; i += 256) m = fmaxf(m, s2[i]);
#pragma unroll
    for (int off = 32; off; off >>= 1) m = fmaxf(m, __shfl_xor(m, off));
    __shared__ float red[4];
    if ((t & 63) == 0) red[t >> 6] = m;
    __syncthreads();
    if (t == 0) {
        float r = fmaxf(fmaxf(red[0], red[1]), fmaxf(red[2], red[3]));
        maxs2[0] = r;
    }
}

// ---------------- k2: repack Wh (fp32 row-major) -> WhB (bf16 B-fragment layout) ----
// WhB[jt][ft][lane][q] = bf16( Wh[jt*32 + (lane>>4)*8 + q][ft*16 + (lane&15)] )
__global__ __launch_bounds__(256) void k_repack(const float* __restrict__ Wh,
                                                short* __restrict__ WhB) {
    int t = blockIdx.x * 256 + threadIdx.x; // 65536 total
    int lane = t & 63, ft = (t >> 6) & 3, jt = t >> 8;
    int g = lane >> 4, r = lane & 15;
    short8 w;
#pragma unroll
    for (int q = 0; q < 8; ++q) {
        float v = Wh[(size_t)(jt * 32 + g * 8 + q) * FOUT + ft * 16 + r];
        w[q] = f2bf(v);
    }
    *((short8*)WhB + t) = w;
}

// ---------------- k3: attention partial over a j-slice ----------------
// Stage adj via __ballot: wave reads 64 contiguous ints (256B coalesced) per
// instruction; ballot compresses to a 64-bit mask parked in the lanes owning
// that row (A-fragment layout). Compute consumes bits from registers.
// grid = (N/32 row-blocks) * NSLICE, block = 128 (2 waves, 16 rows each)
__global__ __launch_bounds__(128) void k_flash(const int* __restrict__ adj,
                                               const short* __restrict__ WhB,
                                               const float* __restrict__ s1,
                                               const float* __restrict__ s2,
                                               const float* __restrict__ maxs2,
                                               float* __restrict__ pO,
                                               float* __restrict__ pl) {
    int rb = blockIdx.x / NSLICE, sl = blockIdx.x % NSLICE;
    int wave = threadIdx.x >> 6, lane = threadIdx.x & 63;
    int r = lane & 15, g = lane >> 4;
    int row = rb * 32 + wave * 16 + r; // row this lane computes p for (A-frag layout)

    __shared__ __align__(16) float s2s[SLICE_J];
    for (int t = threadIdx.x; t < SLICE_J; t += 128) s2s[t] = s2[sl * SLICE_J + t];
    __syncthreads();

    // ---- stage adjacency bits: chunks[w] bit b = (adj[row][sl*1024 + w*64 + b] > 0)
    unsigned long long chunks[16];
    {
        int rbase = rb * 32 + wave * 16;
        const int* abase = adj + (size_t)rbase * N + sl * SLICE_J;
        for (int i = 0; i < 16; ++i) { // dynamic loop: i doesn't index chunks
            const int* ar = abase + (size_t)i * N;
#pragma unroll
            for (int w = 0; w < 16; ++w) {
                unsigned long long bal = __ballot(ar[w * 64 + lane] > 0);
                if (r == i) chunks[w] = bal;
            }
        }
    }

    float s1i = s1[row];
    float xm = s1i + maxs2[0];
    float Mp = fmaxf(xm, 0.2f * xm); // lrelu in log2 domain (scale>0 commutes)

    float l = 0.f;
    f32x4 acc0 = {0.f, 0.f, 0.f, 0.f};
    f32x4 acc1 = {0.f, 0.f, 0.f, 0.f};
    f32x4 acc2 = {0.f, 0.f, 0.f, 0.f};
    f32x4 acc3 = {0.f, 0.f, 0.f, 0.f};

#pragma unroll
    for (int step = 0; step < SLICE_J / 32; ++step) {
        unsigned bits = (unsigned)((chunks[step >> 1] >>
                                    (((step & 1) << 5) + (g << 3))) & 0xffull);
        float4 sv0 = *(const float4*)&s2s[step * 32 + g * 8];
        float4 sv1 = *(const float4*)&s2s[step * 32 + g * 8 + 4];

        short8 af;
        auto pc = [&](unsigned bit, float s2v) -> short {
            float x = s1i + s2v;
            float lr = fmaxf(x, 0.2f * x);      // leaky_relu (log2-scaled domain)
            float p = exp2fast(lr - Mp);        // exp(e - M)
            return bit ? f2bf(p) : (short)0;
        };
        af[0] = pc(bits & 1u, sv0.x);        af[1] = pc((bits >> 1) & 1u, sv0.y);
        af[2] = pc((bits >> 2) & 1u, sv0.z); af[3] = pc((bits >> 3) & 1u, sv0.w);
        af[4] = pc((bits >> 4) & 1u, sv1.x); af[5] = pc((bits >> 5) & 1u, sv1.y);
        af[6] = pc((bits >> 6) & 1u, sv1.z); af[7] = pc((bits >> 7) & 1u, sv1.w);

        l += bf2f(af[0]) + bf2f(af[1]) + bf2f(af[2]) + bf2f(af[3]) +
             bf2f(af[4]) + bf2f(af[5]) + bf2f(af[6]) + bf2f(af[7]);

        int jt = sl * (SLICE_J / 32) + step;
        const short8* bp = (const short8*)WhB + (size_t)jt * 256 + lane;
        acc0 = __builtin_amdgcn_mfma_f32_16x16x32_bf16(af, bp[0], acc0, 0, 0, 0);
        acc1 = __builtin_amdgcn_mfma_f32_16x16x32_bf16(af, bp[64], acc1, 0, 0, 0);
        acc2 = __builtin_amdgcn_mfma_f32_16x16x32_bf16(af, bp[128], acc2, 0, 0, 0);
        acc3 = __builtin_amdgcn_mfma_f32_16x16x32_bf16(af, bp[192], acc3, 0, 0, 0);
    }

    // reduce l across the 4 k-groups (same row lives in lanes r, r+16, r+32, r+48)
    l += __shfl_xor(l, 16);
    l += __shfl_xor(l, 32);

    // write partials: C layout col=lane&15, rows (lane>>4)*4+reg
    int base_row = rb * 32 + wave * 16;
    f32x4 accs[4] = {acc0, acc1, acc2, acc3};
#pragma unroll
    for (int nt = 0; nt < 4; ++nt) {
#pragma unroll
        for (int reg = 0; reg < 4; ++reg) {
            int orow = base_row + g * 4 + reg;
            pO[((size_t)orow * NSLICE + sl) * FOUT + nt * 16 + r] = accs[nt][reg];
        }
    }
    if (lane < 16) pl[(size_t)row * NSLICE + sl] = l;
}

// ---------------- k4: merge partials (plain sum) + ELU ----------------
__global__ __launch_bounds__(256) void k_merge(const float* __restrict__ pO,
                                               const float* __restrict__ pl,
                                               float* __restrict__ out) {
    int t = blockIdx.x * 256 + threadIdx.x;
    int row = t >> 6, f = t & 63;
    float L = 0.f, O = 0.f;
#pragma unroll
    for (int s = 0; s < NSLICE; ++s) {
        L += pl[(size_t)row * NSLICE + s];
        O += pO[((size_t)row * NSLICE + s) * FOUT + f];
    }
    float x = O / L;
    out[t] = x > 0.f ? x : expm1f(x);
}

extern "C" void kernel_launch(void* const* d_in, const int* in_sizes, int n_in,
                              void* d_out, int out_size, void* d_ws, size_t ws_size,
                              hipStream_t stream) {
    const float* h   = (const float*)d_in[0];
    const int*   adj = (const int*)d_in[1];
    const float* W   = (const float*)d_in[2];
    const float* a   = (const float*)d_in[3];
    float* out = (float*)d_out;

    char* ws = (char*)d_ws;
    float* Wh    = (float*)ws;                          // 2 MB
    short* WhB   = (short*)(ws + (2u << 20));           // 1 MB
    float* s1    = (float*)(ws + (3u << 20));           // 32 KB
    float* s2    = (float*)(ws + (3u << 20) + 32768);   // 32 KB
    float* maxs2 = (float*)(ws + (3u << 20) + 65536);   // 4 B
    float* pO    = (float*)(ws + (4u << 20));           // 16 MB
    float* pl    = (float*)(ws + (20u << 20));          // 256 KB

    k_wh<<<N / 4, 256, 0, stream>>>(h, W, a, Wh, s1, s2);
    k_max<<<1, 256, 0, stream>>>(s2, maxs2);
    k_repack<<<(N / 32) * 4 * 64 / 256, 256, 0, stream>>>(Wh, WhB);
    k_flash<<<(N / 32) * NSLICE, 128, 0, stream>>>(adj, WhB, s1, s2, maxs2, pO, pl);
    k_merge<<<N * FOUT / 256, 256, 0, stream>>>(pO, pl, out);
}